// Round 9
// baseline (318.061 us; speedup 1.0000x reference)
//
#include <hip/hip_runtime.h>
#include <hip/hip_bf16.h>
#include <cstddef>
#include <cstdint>

#define BS   16
#define SLEN 512
#define DM   512
#define NH   8
#define DK   64
#define DC   21

typedef __attribute__((ext_vector_type(8))) short short8;     // 8 bf16 = 4 VGPR
typedef __attribute__((ext_vector_type(4))) float f32x4;
typedef __attribute__((ext_vector_type(8))) _Float16 h16x8;   // 8 fp16 = 4 VGPR
typedef _Float16 h16x4a __attribute__((ext_vector_type(4), may_alias)); // aliasing-safe bias load

__device__ inline unsigned pack_bf16(float a, float b) {
    unsigned ua = __builtin_bit_cast(unsigned, a);
    unsigned ub = __builtin_bit_cast(unsigned, b);
    ua = (ua + 0x7fffu + ((ua >> 16) & 1u)) >> 16;            // RNE
    ub = (ub + 0x7fffu + ((ub >> 16) & 1u)) >> 16;
    return ua | (ub << 16);
}
__device__ inline unsigned cvt2(float a, float b) { return pack_bf16(a, b); }
__device__ inline ushort bf16_1(float a) { return (ushort)(pack_bf16(a, 0.f) & 0xffffu); }
__device__ inline unsigned pk_f16(float a, float b) {
    return __builtin_bit_cast(unsigned, __builtin_amdgcn_cvt_pkrtz(a, b));
}

// fp16 bias chunk for (bh, q16-slice): occupies the SAME 32 KiB as the owning
// wave's fp32 attn write range. Segmented per-kt layout:
//   bias entry (ql, k) -> fp16 elem  1024*ql + 32*(k>>4) + (k&15)
// Segment kt (16 fp16) lives inside the 64-byte span that iteration kt's own
// fp32 store (cols [16kt,16kt+16)) covers -> ascending-kt streaming clobbers
// only the segment read earlier in the SAME iteration (program order, same lane).
__device__ __host__ inline size_t bias_chunk_base(int bh, int q16) {
    return 2 * (((size_t)bh * SLEN + (size_t)q16) * SLEN);
}

// ---------------------------------------------------------------------------
// Fused QKV projection GEMM (one dispatch, z selects Q/K/V).
// C[m][n] = sum_k X[m][k]*W[n][k] + bias[n]; BM=64 BN=128 BK=64, 4 waves.
// z=0,1 -> bf16 per-head [bh][s][64] (q,k); z=2 -> fp16 transposed [bh][64][s].
// ---------------------------------------------------------------------------
__global__ __launch_bounds__(256) void gemm_qkv(
    const float* __restrict__ Q, const float* __restrict__ K,
    const float* __restrict__ V,
    const float* __restrict__ Wq, const float* __restrict__ Wk,
    const float* __restrict__ Wv,
    const float* __restrict__ bq, const float* __restrict__ bk,
    const float* __restrict__ bv,
    ushort* __restrict__ qb, ushort* __restrict__ kb, ushort* __restrict__ vt)
{
    __shared__ alignas(16) ushort Atile[64 * 64];
    __shared__ alignas(16) ushort Btile[128 * 64];

    const int z = blockIdx.z;
    const float* X    = (z == 0) ? Q  : (z == 1) ? K  : V;
    const float* W    = (z == 0) ? Wq : (z == 1) ? Wk : Wv;
    const float* bias = (z == 0) ? bq : (z == 1) ? bk : bv;

    const int tid = threadIdx.x;
    const int wave = tid >> 6, lane = tid & 63;
    const int lq = lane & 15, lg = lane >> 4;
    const int wr = wave >> 1, wc = wave & 1;
    const int m0 = blockIdx.x * 64;
    const int n0 = blockIdx.y * 128;

    f32x4 acc[2][4];
#pragma unroll
    for (int i = 0; i < 2; ++i)
#pragma unroll
        for (int j = 0; j < 4; ++j) acc[i][j] = (f32x4){0.f, 0.f, 0.f, 0.f};

    float4 pa[2][2], pb[4][2];

#define LOAD_A(K0)                                                              \
    _Pragma("unroll")                                                           \
    for (int i = 0; i < 2; ++i) {                                               \
        const int P = tid + 256 * i;                                            \
        const int row = P >> 3, cp = P & 7;                                     \
        const float4* s = (const float4*)&X[(size_t)(m0 + row) * 512 + (K0) + cp * 8]; \
        pa[i][0] = s[0]; pa[i][1] = s[1];                                       \
    }
#define LOAD_B(K0)                                                              \
    _Pragma("unroll")                                                           \
    for (int i = 0; i < 4; ++i) {                                               \
        const int P = tid + 256 * i;                                            \
        const int row = P >> 3, cp = P & 7;                                     \
        const float4* s = (const float4*)&W[(size_t)(n0 + row) * 512 + (K0) + cp * 8]; \
        pb[i][0] = s[0]; pb[i][1] = s[1];                                       \
    }

    LOAD_A(0)
    LOAD_B(0)

    for (int it = 0; it < 8; ++it) {
        __syncthreads();
#pragma unroll
        for (int i = 0; i < 2; ++i) {
            const int P = tid + 256 * i;
            const int row = P >> 3, cp = P & 7;
            uint4 w;
            w.x = cvt2(pa[i][0].x, pa[i][0].y);
            w.y = cvt2(pa[i][0].z, pa[i][0].w);
            w.z = cvt2(pa[i][1].x, pa[i][1].y);
            w.w = cvt2(pa[i][1].z, pa[i][1].w);
            *(uint4*)((char*)Atile + row * 128 + 16 * (cp ^ (row & 7))) = w;
        }
#pragma unroll
        for (int i = 0; i < 4; ++i) {
            const int P = tid + 256 * i;
            const int row = P >> 3, cp = P & 7;
            uint4 w;
            w.x = cvt2(pb[i][0].x, pb[i][0].y);
            w.y = cvt2(pb[i][0].z, pb[i][0].w);
            w.z = cvt2(pb[i][1].x, pb[i][1].y);
            w.w = cvt2(pb[i][1].z, pb[i][1].w);
            *(uint4*)((char*)Btile + row * 128 + 16 * (cp ^ (row & 7))) = w;
        }
        __syncthreads();

        if (it < 7) {
            const int kn = (it + 1) * 64;
            LOAD_A(kn)
            LOAD_B(kn)
        }

        short8 af[2][2], bfr[4][2];
#pragma unroll
        for (int mi = 0; mi < 2; ++mi)
#pragma unroll
            for (int kh = 0; kh < 2; ++kh) {
                const int row = wr * 32 + mi * 16 + lq;
                af[mi][kh] = *(const short8*)((const char*)Atile + row * 128 +
                                              16 * ((kh * 4 + lg) ^ (row & 7)));
            }
#pragma unroll
        for (int ni = 0; ni < 4; ++ni)
#pragma unroll
            for (int kh = 0; kh < 2; ++kh) {
                const int row = wc * 64 + ni * 16 + lq;
                bfr[ni][kh] = *(const short8*)((const char*)Btile + row * 128 +
                                               16 * ((kh * 4 + lg) ^ (row & 7)));
            }
        __builtin_amdgcn_s_setprio(1);
#pragma unroll
        for (int kh = 0; kh < 2; ++kh)
#pragma unroll
            for (int mi = 0; mi < 2; ++mi)
#pragma unroll
                for (int ni = 0; ni < 4; ++ni)
                    acc[mi][ni] = __builtin_amdgcn_mfma_f32_16x16x32_bf16(
                        af[mi][kh], bfr[ni][kh], acc[mi][ni], 0, 0, 0);
        __builtin_amdgcn_s_setprio(0);
    }
#undef LOAD_A
#undef LOAD_B

    if (z < 2) {
        ushort* out = (z == 0) ? qb : kb;
#pragma unroll
        for (int mi = 0; mi < 2; ++mi) {
            const int mb = m0 + wr * 32 + mi * 16 + lg * 4;
#pragma unroll
            for (int ni = 0; ni < 4; ++ni) {
                const int n = n0 + wc * 64 + ni * 16 + lq;
                const int h = n >> 6, d = n & 63;
                const float bb = bias[n];
#pragma unroll
                for (int r = 0; r < 4; ++r) {
                    const int m = mb + r;
                    const int bidx = m >> 9, s = m & 511;
                    out[((size_t)(bidx * NH + h) * SLEN + s) * DK + d] =
                        bf16_1(acc[mi][ni][r] + bb);
                }
            }
        }
    } else {
        // fp16 transposed V [bh][64][s]
#pragma unroll
        for (int mi = 0; mi < 2; ++mi) {
            const int mb = m0 + wr * 32 + mi * 16 + lg * 4;
            const int bidx = mb >> 9, s0 = mb & 511;
#pragma unroll
            for (int ni = 0; ni < 4; ++ni) {
                const int n = n0 + wc * 64 + ni * 16 + lq;
                const int h = n >> 6, d = n & 63;
                const float bb = bias[n];
                uint2 pk;
                pk.x = pk_f16(acc[mi][ni][0] + bb, acc[mi][ni][1] + bb);
                pk.y = pk_f16(acc[mi][ni][2] + bb, acc[mi][ni][3] + bb);
                *(uint2*)&vt[((size_t)(bidx * NH + h) * DK + d) * SLEN + s0] = pk;
            }
        }
    }
}

// ---------------------------------------------------------------------------
// Final projection GEMM: bf16 X (concat) -> fp32 out.
// ---------------------------------------------------------------------------
__global__ __launch_bounds__(256) void gemm_out(
    const ushort* __restrict__ Xb, const float* __restrict__ W,
    const float* __restrict__ bias, float* __restrict__ out)
{
    __shared__ alignas(16) ushort Atile[64 * 64];
    __shared__ alignas(16) ushort Btile[128 * 64];

    const int tid = threadIdx.x;
    const int wave = tid >> 6, lane = tid & 63;
    const int lq = lane & 15, lg = lane >> 4;
    const int wr = wave >> 1, wc = wave & 1;
    const int m0 = blockIdx.x * 64;
    const int n0 = blockIdx.y * 128;

    f32x4 acc[2][4];
#pragma unroll
    for (int i = 0; i < 2; ++i)
#pragma unroll
        for (int j = 0; j < 4; ++j) acc[i][j] = (f32x4){0.f, 0.f, 0.f, 0.f};

    uint4  qa[2];
    float4 pb[4][2];

#define LOAD_A(K0)                                                              \
    _Pragma("unroll")                                                           \
    for (int i = 0; i < 2; ++i) {                                               \
        const int P = tid + 256 * i;                                            \
        const int row = P >> 3, sl = P & 7;                                     \
        qa[i] = *(const uint4*)&Xb[(size_t)(m0 + row) * 512 + (K0) + sl * 8];   \
    }
#define LOAD_B(K0)                                                              \
    _Pragma("unroll")                                                           \
    for (int i = 0; i < 4; ++i) {                                               \
        const int P = tid + 256 * i;                                            \
        const int row = P >> 3, cp = P & 7;                                     \
        const float4* s = (const float4*)&W[(size_t)(n0 + row) * 512 + (K0) + cp * 8]; \
        pb[i][0] = s[0]; pb[i][1] = s[1];                                       \
    }

    LOAD_A(0)
    LOAD_B(0)

    for (int it = 0; it < 8; ++it) {
        __syncthreads();
#pragma unroll
        for (int i = 0; i < 2; ++i) {
            const int P = tid + 256 * i;
            const int row = P >> 3, sl = P & 7;
            *(uint4*)((char*)Atile + row * 128 + 16 * (sl ^ (row & 7))) = qa[i];
        }
#pragma unroll
        for (int i = 0; i < 4; ++i) {
            const int P = tid + 256 * i;
            const int row = P >> 3, cp = P & 7;
            uint4 w;
            w.x = cvt2(pb[i][0].x, pb[i][0].y);
            w.y = cvt2(pb[i][0].z, pb[i][0].w);
            w.z = cvt2(pb[i][1].x, pb[i][1].y);
            w.w = cvt2(pb[i][1].z, pb[i][1].w);
            *(uint4*)((char*)Btile + row * 128 + 16 * (cp ^ (row & 7))) = w;
        }
        __syncthreads();

        if (it < 7) {
            const int kn = (it + 1) * 64;
            LOAD_A(kn)
            LOAD_B(kn)
        }

        short8 af[2][2], bfr[4][2];
#pragma unroll
        for (int mi = 0; mi < 2; ++mi)
#pragma unroll
            for (int kh = 0; kh < 2; ++kh) {
                const int row = wr * 32 + mi * 16 + lq;
                af[mi][kh] = *(const short8*)((const char*)Atile + row * 128 +
                                              16 * ((kh * 4 + lg) ^ (row & 7)));
            }
#pragma unroll
        for (int ni = 0; ni < 4; ++ni)
#pragma unroll
            for (int kh = 0; kh < 2; ++kh) {
                const int row = wc * 64 + ni * 16 + lq;
                bfr[ni][kh] = *(const short8*)((const char*)Btile + row * 128 +
                                               16 * ((kh * 4 + lg) ^ (row & 7)));
            }
        __builtin_amdgcn_s_setprio(1);
#pragma unroll
        for (int kh = 0; kh < 2; ++kh)
#pragma unroll
            for (int mi = 0; mi < 2; ++mi)
#pragma unroll
                for (int ni = 0; ni < 4; ++ni)
                    acc[mi][ni] = __builtin_amdgcn_mfma_f32_16x16x32_bf16(
                        af[mi][kh], bfr[ni][kh], acc[mi][ni], 0, 0, 0);
        __builtin_amdgcn_s_setprio(0);
    }
#undef LOAD_A
#undef LOAD_B

#pragma unroll
    for (int mi = 0; mi < 2; ++mi) {
        const int mb = m0 + wr * 32 + mi * 16 + lg * 4;
#pragma unroll
        for (int ni = 0; ni < 4; ++ni) {
            const int n = n0 + wc * 64 + ni * 16 + lq;
            const float bb = bias[n];
#pragma unroll
            for (int r = 0; r < 4; ++r)
                out[(size_t)(mb + r) * 512 + n] = acc[mi][ni][r] + bb;
        }
    }
}

// ---------------------------------------------------------------------------
// Bias -> fp16, per-kt segmented layout inside the attn region.
// ---------------------------------------------------------------------------
__global__ __launch_bounds__(512) void bias_kernel(
    const float* __restrict__ dtw, const float* __restrict__ Wd,
    const float* __restrict__ bd, _Float16* __restrict__ bias16)
{
    __shared__ float wdl[NH * DC];
    __shared__ float bdl[NH];
    const int k = threadIdx.x;
    const int q = blockIdx.x;
    const int b = blockIdx.y;
    if (k < NH * DC) wdl[k] = Wd[k];
    if (k < NH) bdl[k] = bd[k];
    __syncthreads();

    float acc[NH];
#pragma unroll
    for (int h = 0; h < NH; ++h) acc[h] = bdl[h];

    const float* p = dtw + ((size_t)b * DC * SLEN + q) * SLEN + k;
#pragma unroll
    for (int c = 0; c < DC; ++c) {
        const float x = p[(size_t)c * SLEN * SLEN];
#pragma unroll
        for (int h = 0; h < NH; ++h) acc[h] += x * wdl[h * DC + c];
    }
    const int q16 = q & ~15, ql = q & 15;
    const size_t seg = 1024 * (size_t)ql + 32 * (size_t)(k >> 4) + (k & 15);
#pragma unroll
    for (int h = 0; h < NH; ++h) {
        const size_t base = bias_chunk_base(b * NH + h, q16);
        bias16[base + seg] = (_Float16)acc[h];
    }
}

// ---------------------------------------------------------------------------
// One-pass streaming MFMA attention: per kt {QK^T, +bias, exp, store e
// (unnormalized fp32), pack fp16 -> LDS bounce}; per kt-pair: 4 PV MFMA.
// Then reduce sum, vmcnt(0), normalize the just-written rows (L2-hot),
// write concat. No sc[32], 8 KB LDS, VGPR ~100 -> 4 blocks/CU.
// ---------------------------------------------------------------------------
__global__ __launch_bounds__(256, 4) void attn_mfma(
    const ushort* __restrict__ qb, const ushort* __restrict__ kb,
    const ushort* __restrict__ vt, float* __restrict__ attn,
    ushort* __restrict__ concat)
{
    __shared__ alignas(16) ushort Pbuf[4][2][16][32];   // 8 KB

    const int tid = threadIdx.x;
    const int wave = tid >> 6;
    const int lane = tid & 63;
    const int lq = lane & 15;
    const int lg = lane >> 4;

    // XCD swizzle: 8 consecutive dispatches per XCD share one (b,h)
    const unsigned l = blockIdx.x;
    const int g  = (int)((l & 7) + 8 * (l >> 6));
    const int qt = (int)((l >> 3) & 7);
    const int h = g & 7, b = g >> 3;
    const int bh = b * NH + h;
    const int q0 = qt * 64 + wave * 16;

    const ushort* qptr = qb + ((size_t)bh * SLEN + q0) * DK;
    const ushort* kptr = kb + (size_t)bh * SLEN * DK;
    const ushort* vptr = vt + (size_t)bh * DK * SLEN;   // fp16 bits
    float* attn_b = attn + ((size_t)bh * SLEN + q0) * SLEN;
    const _Float16* bias_row =
        (const _Float16*)attn + bias_chunk_base(bh, q0) + 1024 * (size_t)lq;

    const short8 qf0 = *(const short8*)&qptr[(size_t)lq * DK + lg * 8];
    const short8 qf1 = *(const short8*)&qptr[(size_t)lq * DK + lg * 8 + 32];

    float sum = 0.f;
    f32x4 oacc[4] = {{0.f,0.f,0.f,0.f},{0.f,0.f,0.f,0.f},{0.f,0.f,0.f,0.f},{0.f,0.f,0.f,0.f}};

    for (int c2 = 0; c2 < 16; ++c2) {
        char* pb = (char*)&Pbuf[wave][c2 & 1][0][0];
#pragma unroll
        for (int t = 0; t < 2; ++t) {
            const int kt = 2 * c2 + t;
            const short8 a0 = *(const short8*)&kptr[(size_t)(kt * 16 + lq) * DK + lg * 8];
            const short8 a1 = *(const short8*)&kptr[(size_t)(kt * 16 + lq) * DK + lg * 8 + 32];
            f32x4 c = {0.f, 0.f, 0.f, 0.f};
            c = __builtin_amdgcn_mfma_f32_16x16x32_bf16(a0, qf0, c, 0, 0, 0);
            c = __builtin_amdgcn_mfma_f32_16x16x32_bf16(a1, qf1, c, 0, 0, 0);
            const h16x4a b4 = *(const h16x4a*)&bias_row[32 * kt + 4 * lg];
            f32x4 e;
            e[0] = __expf(c[0] * 0.125f + (float)b4[0]);
            e[1] = __expf(c[1] * 0.125f + (float)b4[1]);
            e[2] = __expf(c[2] * 0.125f + (float)b4[2]);
            e[3] = __expf(c[3] * 0.125f + (float)b4[3]);
            sum += (e[0] + e[1]) + (e[2] + e[3]);
            // unnormalized store; clobbers exactly bias segment kt (already read)
            *(f32x4*)&attn_b[(size_t)lq * SLEN + kt * 16 + lg * 4] = e;
            uint2 pk;
            pk.x = pk_f16(e[0], e[1]);
            pk.y = pk_f16(e[2], e[3]);
            const int slot = (t * 2 + (lg >> 1)) ^ (lq & 3);
            *(uint2*)(pb + lq * 64 + slot * 16 + (lg & 1) * 8) = pk;
        }
        asm volatile("s_waitcnt lgkmcnt(0)" ::: "memory");

        const h16x8 pa = *(const h16x8*)(pb + lq * 64 + (lg ^ (lq & 3)) * 16);
        __builtin_amdgcn_s_setprio(1);
#pragma unroll
        for (int dt = 0; dt < 4; ++dt) {
            const h16x8 vb8 = *(const h16x8*)&vptr[(size_t)(dt * 16 + lq) * SLEN + c2 * 32 + lg * 8];
            oacc[dt] = __builtin_amdgcn_mfma_f32_16x16x32_f16(pa, vb8, oacc[dt], 0, 0, 0);
        }
        __builtin_amdgcn_s_setprio(0);
    }

    sum += __shfl_xor(sum, 16);
    sum += __shfl_xor(sum, 32);
    const float inv = 1.0f / sum;

    // drain our stores, then normalize our own rows (L2-hot)
    asm volatile("s_waitcnt vmcnt(0)" ::: "memory");
#pragma unroll 8
    for (int i = 0; i < 32; ++i) {
        float* p = &attn_b[(size_t)lq * SLEN + i * 16 + lg * 4];
        f32x4 v = *(f32x4*)p;
        *(f32x4*)p = v * inv;
    }

    // concat in bf16 [b][s][h*64+d]
    ushort* cbase = concat + ((size_t)(b * SLEN + q0)) * DM + h * 64;
#pragma unroll
    for (int r = 0; r < 4; ++r) {
        const float iv = __shfl(inv, lg * 4 + r);
#pragma unroll
        for (int dt = 0; dt < 4; ++dt) {
            cbase[(size_t)(lg * 4 + r) * DM + dt * 16 + lq] = bf16_1(oacc[dt][r] * iv);
        }
    }
}

// ---------------------------------------------------------------------------
extern "C" void kernel_launch(void* const* d_in, const int* in_sizes, int n_in,
                              void* d_out, int out_size, void* d_ws, size_t ws_size,
                              hipStream_t stream)
{
    const float* Q   = (const float*)d_in[0];
    const float* K   = (const float*)d_in[1];
    const float* V   = (const float*)d_in[2];
    const float* dtw = (const float*)d_in[4];
    const float* Wq  = (const float*)d_in[5];
    const float* bq  = (const float*)d_in[6];
    const float* Wk  = (const float*)d_in[7];
    const float* bk  = (const float*)d_in[8];
    const float* Wv  = (const float*)d_in[9];
    const float* bv  = (const float*)d_in[10];
    const float* Wd  = (const float*)d_in[11];
    const float* bd  = (const float*)d_in[12];
    const float* Wo  = (const float*)d_in[13];
    const float* bo  = (const float*)d_in[14];

    float* out  = (float*)d_out;                       // [16,512,512] fp32
    float* attn = out + (size_t)BS * SLEN * DM;        // [16,8,512,512] fp32
    _Float16* bias16 = (_Float16*)attn;                // fp16 bias chunks inside attn region

    const size_t PHS = (size_t)BS * NH * SLEN * DK;    // 4,194,304 elements
    ushort* qb = (ushort*)d_ws;
    ushort* kb = qb + PHS;
    ushort* vt = kb + PHS;                             // fp16 V
    ushort* cb = vt + PHS;                             // concat bf16 [16,512,512]

    gemm_qkv<<<dim3(128, 4, 3), 256, 0, stream>>>(Q, K, V, Wq, Wk, Wv,
                                                  bq, bk, bv, qb, kb, vt);

    bias_kernel<<<dim3(SLEN, BS), 512, 0, stream>>>(dtw, Wd, bd, bias16);

    attn_mfma<<<dim3(1024), 256, 0, stream>>>(qb, kb, vt, attn, cb);

    gemm_out<<<dim3(128, 4), 256, 0, stream>>>(cb, Wo, bo, out);
}

// Round 10
// 253.204 us; speedup vs baseline: 1.2561x; 1.2561x over previous
//
#include <hip/hip_runtime.h>
#include <hip/hip_bf16.h>
#include <cstddef>
#include <cstdint>

#define BS   16
#define SLEN 512
#define DM   512
#define NH   8
#define DK   64
#define DC   21

typedef __attribute__((ext_vector_type(8))) short short8;     // 8 bf16 = 4 VGPR
typedef __attribute__((ext_vector_type(4))) float f32x4;
typedef __attribute__((ext_vector_type(8))) _Float16 h16x8;   // 8 fp16 = 4 VGPR
typedef __attribute__((ext_vector_type(4))) _Float16 h16x4;   // 4 fp16 = 2 VGPR
typedef __attribute__((ext_vector_type(2))) unsigned u32x2;   // packed 4 fp16
typedef _Float16 h16x4a __attribute__((ext_vector_type(4), may_alias)); // aliasing-safe bias load

__device__ inline unsigned pack_bf16(float a, float b) {
    unsigned ua = __builtin_bit_cast(unsigned, a);
    unsigned ub = __builtin_bit_cast(unsigned, b);
    ua = (ua + 0x7fffu + ((ua >> 16) & 1u)) >> 16;            // RNE
    ub = (ub + 0x7fffu + ((ub >> 16) & 1u)) >> 16;
    return ua | (ub << 16);
}
__device__ inline unsigned cvt2(float a, float b) { return pack_bf16(a, b); }
__device__ inline ushort bf16_1(float a) { return (ushort)(pack_bf16(a, 0.f) & 0xffffu); }
__device__ inline unsigned pk_f16(float a, float b) {
    return __builtin_bit_cast(unsigned, __builtin_amdgcn_cvt_pkrtz(a, b));
}

// fp16 bias chunk for (bh, q16-slice): occupies the first half of the owning
// wave's 32 KiB fp32 attn write range. Linear layout (ql*SLEN + k). Safe:
// in attn_mfma ALL bias reads complete (registers) before ANY attn store.
__device__ __host__ inline size_t bias_chunk_base(int bh, int q16) {
    return 2 * (((size_t)bh * SLEN + (size_t)q16) * SLEN);
}

// ---------------------------------------------------------------------------
// bf16 MFMA GEMM. MODE 1: fp32 X -> bf16 per-head [bh][s][64].
// MODE 2: fp32 X -> fp16 transposed [bh][64][s] (V). MODE 3: bf16 X -> fp32.
// ---------------------------------------------------------------------------
template<int MODE>
__global__ __launch_bounds__(256) void gemm_bf16(
    const void* __restrict__ Xv, const float* __restrict__ W,
    const float* __restrict__ bias, void* __restrict__ outv)
{
    __shared__ alignas(16) ushort Atile[64 * 64];
    __shared__ alignas(16) ushort Btile[128 * 64];

    const float*  Xf = (const float*)Xv;
    const ushort* Xb = (const ushort*)Xv;

    const int tid = threadIdx.x;
    const int wave = tid >> 6, lane = tid & 63;
    const int lq = lane & 15, lg = lane >> 4;
    const int wr = wave >> 1, wc = wave & 1;
    const int m0 = blockIdx.x * 64;
    const int n0 = blockIdx.y * 128;

    f32x4 acc[2][4];
#pragma unroll
    for (int i = 0; i < 2; ++i)
#pragma unroll
        for (int j = 0; j < 4; ++j) acc[i][j] = (f32x4){0.f, 0.f, 0.f, 0.f};

    float4 pa[2][2], pb[4][2];
    uint4  qa[2];

#define LOAD_A(K0)                                                              \
    if (MODE == 3) {                                                            \
        _Pragma("unroll")                                                       \
        for (int i = 0; i < 2; ++i) {                                           \
            const int P = tid + 256 * i;                                        \
            const int row = P >> 3, sl = P & 7;                                 \
            qa[i] = *(const uint4*)&Xb[(size_t)(m0 + row) * 512 + (K0) + sl * 8]; \
        }                                                                       \
    } else {                                                                    \
        _Pragma("unroll")                                                       \
        for (int i = 0; i < 2; ++i) {                                           \
            const int P = tid + 256 * i;                                        \
            const int row = P >> 3, cp = P & 7;                                 \
            const float4* s = (const float4*)&Xf[(size_t)(m0 + row) * 512 + (K0) + cp * 8]; \
            pa[i][0] = s[0]; pa[i][1] = s[1];                                   \
        }                                                                       \
    }
#define LOAD_B(K0)                                                              \
    _Pragma("unroll")                                                           \
    for (int i = 0; i < 4; ++i) {                                               \
        const int P = tid + 256 * i;                                            \
        const int row = P >> 3, cp = P & 7;                                     \
        const float4* s = (const float4*)&W[(size_t)(n0 + row) * 512 + (K0) + cp * 8]; \
        pb[i][0] = s[0]; pb[i][1] = s[1];                                       \
    }

    LOAD_A(0)
    LOAD_B(0)

    for (int it = 0; it < 8; ++it) {
        __syncthreads();
        if (MODE == 3) {
#pragma unroll
            for (int i = 0; i < 2; ++i) {
                const int P = tid + 256 * i;
                const int row = P >> 3, sl = P & 7;
                *(uint4*)((char*)Atile + row * 128 + 16 * (sl ^ (row & 7))) = qa[i];
            }
        } else {
#pragma unroll
            for (int i = 0; i < 2; ++i) {
                const int P = tid + 256 * i;
                const int row = P >> 3, cp = P & 7;
                uint4 w;
                w.x = cvt2(pa[i][0].x, pa[i][0].y);
                w.y = cvt2(pa[i][0].z, pa[i][0].w);
                w.z = cvt2(pa[i][1].x, pa[i][1].y);
                w.w = cvt2(pa[i][1].z, pa[i][1].w);
                *(uint4*)((char*)Atile + row * 128 + 16 * (cp ^ (row & 7))) = w;
            }
        }
#pragma unroll
        for (int i = 0; i < 4; ++i) {
            const int P = tid + 256 * i;
            const int row = P >> 3, cp = P & 7;
            uint4 w;
            w.x = cvt2(pb[i][0].x, pb[i][0].y);
            w.y = cvt2(pb[i][0].z, pb[i][0].w);
            w.z = cvt2(pb[i][1].x, pb[i][1].y);
            w.w = cvt2(pb[i][1].z, pb[i][1].w);
            *(uint4*)((char*)Btile + row * 128 + 16 * (cp ^ (row & 7))) = w;
        }
        __syncthreads();

        if (it < 7) {
            const int kn = (it + 1) * 64;
            LOAD_A(kn)
            LOAD_B(kn)
        }

        short8 af[2][2], bfr[4][2];
#pragma unroll
        for (int mi = 0; mi < 2; ++mi)
#pragma unroll
            for (int kh = 0; kh < 2; ++kh) {
                const int row = wr * 32 + mi * 16 + lq;
                af[mi][kh] = *(const short8*)((const char*)Atile + row * 128 +
                                              16 * ((kh * 4 + lg) ^ (row & 7)));
            }
#pragma unroll
        for (int ni = 0; ni < 4; ++ni)
#pragma unroll
            for (int kh = 0; kh < 2; ++kh) {
                const int row = wc * 64 + ni * 16 + lq;
                bfr[ni][kh] = *(const short8*)((const char*)Btile + row * 128 +
                                               16 * ((kh * 4 + lg) ^ (row & 7)));
            }
        __builtin_amdgcn_s_setprio(1);
#pragma unroll
        for (int kh = 0; kh < 2; ++kh)
#pragma unroll
            for (int mi = 0; mi < 2; ++mi)
#pragma unroll
                for (int ni = 0; ni < 4; ++ni)
                    acc[mi][ni] = __builtin_amdgcn_mfma_f32_16x16x32_bf16(
                        af[mi][kh], bfr[ni][kh], acc[mi][ni], 0, 0, 0);
        __builtin_amdgcn_s_setprio(0);
    }
#undef LOAD_A
#undef LOAD_B

    if (MODE == 3) {
        float* out = (float*)outv;
#pragma unroll
        for (int mi = 0; mi < 2; ++mi) {
            const int mb = m0 + wr * 32 + mi * 16 + lg * 4;
#pragma unroll
            for (int ni = 0; ni < 4; ++ni) {
                const int n = n0 + wc * 64 + ni * 16 + lq;
                const float bb = bias[n];
#pragma unroll
                for (int r = 0; r < 4; ++r)
                    out[(size_t)(mb + r) * 512 + n] = acc[mi][ni][r] + bb;
            }
        }
    } else if (MODE == 1) {
        ushort* out = (ushort*)outv;
#pragma unroll
        for (int mi = 0; mi < 2; ++mi) {
            const int mb = m0 + wr * 32 + mi * 16 + lg * 4;
#pragma unroll
            for (int ni = 0; ni < 4; ++ni) {
                const int n = n0 + wc * 64 + ni * 16 + lq;
                const int h = n >> 6, d = n & 63;
                const float bb = bias[n];
#pragma unroll
                for (int r = 0; r < 4; ++r) {
                    const int m = mb + r;
                    const int bidx = m >> 9, s = m & 511;
                    out[((size_t)(bidx * NH + h) * SLEN + s) * DK + d] =
                        bf16_1(acc[mi][ni][r] + bb);
                }
            }
        }
    } else {
        // MODE 2: fp16 transposed V [bh][64][s]
        ushort* out = (ushort*)outv;
#pragma unroll
        for (int mi = 0; mi < 2; ++mi) {
            const int mb = m0 + wr * 32 + mi * 16 + lg * 4;
            const int bidx = mb >> 9, s0 = mb & 511;
#pragma unroll
            for (int ni = 0; ni < 4; ++ni) {
                const int n = n0 + wc * 64 + ni * 16 + lq;
                const int h = n >> 6, d = n & 63;
                const float bb = bias[n];
                uint2 pk;
                pk.x = pk_f16(acc[mi][ni][0] + bb, acc[mi][ni][1] + bb);
                pk.y = pk_f16(acc[mi][ni][2] + bb, acc[mi][ni][3] + bb);
                *(uint2*)&out[((size_t)(bidx * NH + h) * DK + d) * SLEN + s0] = pk;
            }
        }
    }
}

// ---------------------------------------------------------------------------
// Bias -> fp16, linear layout inside the attn region (see bias_chunk_base).
// ---------------------------------------------------------------------------
__global__ __launch_bounds__(512) void bias_kernel(
    const float* __restrict__ dtw, const float* __restrict__ Wd,
    const float* __restrict__ bd, _Float16* __restrict__ bias16)
{
    __shared__ float wdl[NH * DC];
    __shared__ float bdl[NH];
    const int k = threadIdx.x;
    const int q = blockIdx.x;
    const int b = blockIdx.y;
    if (k < NH * DC) wdl[k] = Wd[k];
    if (k < NH) bdl[k] = bd[k];
    __syncthreads();

    float acc[NH];
#pragma unroll
    for (int h = 0; h < NH; ++h) acc[h] = bdl[h];

    const float* p = dtw + ((size_t)b * DC * SLEN + q) * SLEN + k;
#pragma unroll
    for (int c = 0; c < DC; ++c) {
        const float x = p[(size_t)c * SLEN * SLEN];
#pragma unroll
        for (int h = 0; h < NH; ++h) acc[h] += x * wdl[h * DC + c];
    }
    const int q16 = q & ~15, ql = q & 15;
#pragma unroll
    for (int h = 0; h < NH; ++h) {
        const size_t base = bias_chunk_base(b * NH + h, q16);
        bias16[base + (size_t)ql * SLEN + k] = (_Float16)acc[h];
    }
}

// ---------------------------------------------------------------------------
// One-pass MFMA attention, packed-fp16 score registers (no sc[32]).
// QK^T loop: scores -> exp -> pack fp16 into ep[32] (64 VGPR); sum in f32.
// After sum reduce: per kt-pair {unpack ep*inv -> fp32 attn store; LDS bounce
// (1KB/wave dbuf) -> 4 PV f16 MFMA}. Same work/traffic as r6 champion but
// VGPR ~200 -> <=168 and LDS 64KB -> 8KB (occupancy 2 -> 3 waves/SIMD).
// All bias reads precede all attn stores -> aliasing trivially safe.
// ---------------------------------------------------------------------------
__global__ __launch_bounds__(256, 3) void attn_mfma(
    const ushort* __restrict__ qb, const ushort* __restrict__ kb,
    const ushort* __restrict__ vt, float* __restrict__ attn,
    ushort* __restrict__ concat)
{
    __shared__ alignas(16) ushort Pbuf[4][2][16][32];   // 8 KB

    const int tid = threadIdx.x;
    const int wave = tid >> 6;
    const int lane = tid & 63;
    const int lq = lane & 15;
    const int lg = lane >> 4;

    // XCD swizzle: 8 consecutive dispatches per XCD share one (b,h)
    const unsigned l = blockIdx.x;
    const int g  = (int)((l & 7) + 8 * (l >> 6));
    const int qt = (int)((l >> 3) & 7);
    const int h = g & 7, b = g >> 3;
    const int bh = b * NH + h;
    const int q0 = qt * 64 + wave * 16;

    const ushort* qptr = qb + ((size_t)bh * SLEN + q0) * DK;
    const ushort* kptr = kb + (size_t)bh * SLEN * DK;
    const ushort* vptr = vt + (size_t)bh * DK * SLEN;   // fp16 bits
    float* attn_b = attn + ((size_t)bh * SLEN + q0) * SLEN;
    const _Float16* bias_row =
        (const _Float16*)attn + bias_chunk_base(bh, q0) + (size_t)lq * SLEN;

    const short8 qf0 = *(const short8*)&qptr[(size_t)lq * DK + lg * 8];
    const short8 qf1 = *(const short8*)&qptr[(size_t)lq * DK + lg * 8 + 32];

    float sum = 0.f;
    u32x2 ep[32];                       // packed fp16 e (64 VGPR)

#pragma unroll
    for (int kt = 0; kt < 32; ++kt) {
        const short8 a0 = *(const short8*)&kptr[(size_t)(kt * 16 + lq) * DK + lg * 8];
        const short8 a1 = *(const short8*)&kptr[(size_t)(kt * 16 + lq) * DK + lg * 8 + 32];
        f32x4 c = {0.f, 0.f, 0.f, 0.f};
        c = __builtin_amdgcn_mfma_f32_16x16x32_bf16(a0, qf0, c, 0, 0, 0);
        c = __builtin_amdgcn_mfma_f32_16x16x32_bf16(a1, qf1, c, 0, 0, 0);
        const h16x4a b4 = *(const h16x4a*)&bias_row[kt * 16 + 4 * lg];
        const float e0 = __expf(c[0] * 0.125f + (float)b4[0]);
        const float e1 = __expf(c[1] * 0.125f + (float)b4[1]);
        const float e2 = __expf(c[2] * 0.125f + (float)b4[2]);
        const float e3 = __expf(c[3] * 0.125f + (float)b4[3]);
        sum += (e0 + e1) + (e2 + e3);
        u32x2 pk;
        pk[0] = pk_f16(e0, e1);
        pk[1] = pk_f16(e2, e3);
        ep[kt] = pk;
    }
    sum += __shfl_xor(sum, 16);
    sum += __shfl_xor(sum, 32);
    const float inv = 1.0f / sum;

    f32x4 oacc[4] = {{0.f,0.f,0.f,0.f},{0.f,0.f,0.f,0.f},{0.f,0.f,0.f,0.f},{0.f,0.f,0.f,0.f}};

#pragma unroll
    for (int c2 = 0; c2 < 16; ++c2) {
        char* pb = (char*)&Pbuf[wave][c2 & 1][0][0];
#pragma unroll
        for (int t = 0; t < 2; ++t) {
            const int kt = 2 * c2 + t;
            // fp32 attn store = unpack(fp16 e) * inv
            const h16x4 hv = __builtin_bit_cast(h16x4, ep[kt]);
            f32x4 a;
            a[0] = (float)hv[0] * inv;
            a[1] = (float)hv[1] * inv;
            a[2] = (float)hv[2] * inv;
            a[3] = (float)hv[3] * inv;
            *(f32x4*)&attn_b[(size_t)lq * SLEN + kt * 16 + lg * 4] = a;
            // LDS bounce (layout identical to validated r9 path)
            const int slot = (t * 2 + (lg >> 1)) ^ (lq & 3);
            *(u32x2*)(pb + lq * 64 + slot * 16 + (lg & 1) * 8) = ep[kt];
        }
        asm volatile("s_waitcnt lgkmcnt(0)" ::: "memory");

        const h16x8 pa = *(const h16x8*)(pb + lq * 64 + (lg ^ (lq & 3)) * 16);
        __builtin_amdgcn_s_setprio(1);
#pragma unroll
        for (int dt = 0; dt < 4; ++dt) {
            const h16x8 vb8 = *(const h16x8*)&vptr[(size_t)(dt * 16 + lq) * SLEN + c2 * 32 + lg * 8];
            oacc[dt] = __builtin_amdgcn_mfma_f32_16x16x32_f16(pa, vb8, oacc[dt], 0, 0, 0);
        }
        __builtin_amdgcn_s_setprio(0);
    }

    // concat in bf16 [b][s][h*64+d]
    ushort* cbase = concat + ((size_t)(b * SLEN + q0)) * DM + h * 64;
#pragma unroll
    for (int r = 0; r < 4; ++r) {
        const float iv = __shfl(inv, lg * 4 + r);
#pragma unroll
        for (int dt = 0; dt < 4; ++dt) {
            cbase[(size_t)(lg * 4 + r) * DM + dt * 16 + lq] = bf16_1(oacc[dt][r] * iv);
        }
    }
}

// ---------------------------------------------------------------------------
extern "C" void kernel_launch(void* const* d_in, const int* in_sizes, int n_in,
                              void* d_out, int out_size, void* d_ws, size_t ws_size,
                              hipStream_t stream)
{
    const float* Q   = (const float*)d_in[0];
    const float* K   = (const float*)d_in[1];
    const float* V   = (const float*)d_in[2];
    const float* dtw = (const float*)d_in[4];
    const float* Wq  = (const float*)d_in[5];
    const float* bq  = (const float*)d_in[6];
    const float* Wk  = (const float*)d_in[7];
    const float* bk  = (const float*)d_in[8];
    const float* Wv  = (const float*)d_in[9];
    const float* bv  = (const float*)d_in[10];
    const float* Wd  = (const float*)d_in[11];
    const float* bd  = (const float*)d_in[12];
    const float* Wo  = (const float*)d_in[13];
    const float* bo  = (const float*)d_in[14];

    float* out  = (float*)d_out;                       // [16,512,512] fp32
    float* attn = out + (size_t)BS * SLEN * DM;        // [16,8,512,512] fp32
    _Float16* bias16 = (_Float16*)attn;                // fp16 bias chunks inside attn region

    const size_t PHS = (size_t)BS * NH * SLEN * DK;    // 4,194,304 elements
    ushort* qb = (ushort*)d_ws;
    ushort* kb = qb + PHS;
    ushort* vt = kb + PHS;                             // fp16 V
    ushort* cb = vt + PHS;                             // concat bf16 [16,512,512]

    const dim3 gemm_grid(128, 4);

    gemm_bf16<1><<<gemm_grid, 256, 0, stream>>>(Q, Wq, bq, qb);
    gemm_bf16<1><<<gemm_grid, 256, 0, stream>>>(K, Wk, bk, kb);
    gemm_bf16<2><<<gemm_grid, 256, 0, stream>>>(V, Wv, bv, vt);

    bias_kernel<<<dim3(SLEN, BS), 512, 0, stream>>>(dtw, Wd, bd, bias16);

    attn_mfma<<<dim3(1024), 256, 0, stream>>>(qb, kb, vt, attn, cb);

    gemm_bf16<3><<<gemm_grid, 256, 0, stream>>>(cb, Wo, bo, out);
}

// Round 11
// 241.738 us; speedup vs baseline: 1.3157x; 1.0474x over previous
//
#include <hip/hip_runtime.h>
#include <hip/hip_bf16.h>
#include <cstddef>
#include <cstdint>

#define BS   16
#define SLEN 512
#define DM   512
#define NH   8
#define DK   64
#define DC   21

typedef __attribute__((ext_vector_type(8))) short short8;     // 8 bf16 = 4 VGPR
typedef __attribute__((ext_vector_type(4))) float f32x4;
typedef __attribute__((ext_vector_type(8))) _Float16 h16x8;   // 8 fp16 = 4 VGPR
typedef __attribute__((ext_vector_type(4))) _Float16 h16x4;   // 4 fp16 = 2 VGPR
typedef __attribute__((ext_vector_type(2))) unsigned u32x2;   // packed 4 fp16
typedef _Float16 h16x4a __attribute__((ext_vector_type(4), may_alias)); // aliasing-safe bias load

__device__ inline unsigned pack_bf16(float a, float b) {
    unsigned ua = __builtin_bit_cast(unsigned, a);
    unsigned ub = __builtin_bit_cast(unsigned, b);
    ua = (ua + 0x7fffu + ((ua >> 16) & 1u)) >> 16;            // RNE
    ub = (ub + 0x7fffu + ((ub >> 16) & 1u)) >> 16;
    return ua | (ub << 16);
}
__device__ inline unsigned cvt2(float a, float b) { return pack_bf16(a, b); }
__device__ inline ushort bf16_1(float a) { return (ushort)(pack_bf16(a, 0.f) & 0xffffu); }
__device__ inline unsigned pk_f16(float a, float b) {
    return __builtin_bit_cast(unsigned, __builtin_amdgcn_cvt_pkrtz(a, b));
}

// fp16 bias chunk for (bh, 16-row q-slice): first half of that slice's 32 KiB
// fp32 attn write range, linear (ql*SLEN + k). Safe: in attn_mfma ALL bias
// reads complete before the post-barrier attn stores begin.
__device__ __host__ inline size_t bias_chunk_base(int bh, int q16) {
    return 2 * (((size_t)bh * SLEN + (size_t)q16) * SLEN);
}

// ---------------------------------------------------------------------------
// Fused QKV projection GEMM (one dispatch, z selects Q/K/V). Validated r9.
// z=0,1 -> bf16 per-head [bh][s][64] (q,k); z=2 -> fp16 transposed [bh][64][s].
// ---------------------------------------------------------------------------
__global__ __launch_bounds__(256) void gemm_qkv(
    const float* __restrict__ Q, const float* __restrict__ K,
    const float* __restrict__ V,
    const float* __restrict__ Wq, const float* __restrict__ Wk,
    const float* __restrict__ Wv,
    const float* __restrict__ bq, const float* __restrict__ bk,
    const float* __restrict__ bv,
    ushort* __restrict__ qb, ushort* __restrict__ kb, ushort* __restrict__ vt)
{
    __shared__ alignas(16) ushort Atile[64 * 64];
    __shared__ alignas(16) ushort Btile[128 * 64];

    const int z = blockIdx.z;
    const float* X    = (z == 0) ? Q  : (z == 1) ? K  : V;
    const float* W    = (z == 0) ? Wq : (z == 1) ? Wk : Wv;
    const float* bias = (z == 0) ? bq : (z == 1) ? bk : bv;

    const int tid = threadIdx.x;
    const int wave = tid >> 6, lane = tid & 63;
    const int lq = lane & 15, lg = lane >> 4;
    const int wr = wave >> 1, wc = wave & 1;
    const int m0 = blockIdx.x * 64;
    const int n0 = blockIdx.y * 128;

    f32x4 acc[2][4];
#pragma unroll
    for (int i = 0; i < 2; ++i)
#pragma unroll
        for (int j = 0; j < 4; ++j) acc[i][j] = (f32x4){0.f, 0.f, 0.f, 0.f};

    float4 pa[2][2], pb[4][2];

#define LOAD_A(K0)                                                              \
    _Pragma("unroll")                                                           \
    for (int i = 0; i < 2; ++i) {                                               \
        const int P = tid + 256 * i;                                            \
        const int row = P >> 3, cp = P & 7;                                     \
        const float4* s = (const float4*)&X[(size_t)(m0 + row) * 512 + (K0) + cp * 8]; \
        pa[i][0] = s[0]; pa[i][1] = s[1];                                       \
    }
#define LOAD_B(K0)                                                              \
    _Pragma("unroll")                                                           \
    for (int i = 0; i < 4; ++i) {                                               \
        const int P = tid + 256 * i;                                            \
        const int row = P >> 3, cp = P & 7;                                     \
        const float4* s = (const float4*)&W[(size_t)(n0 + row) * 512 + (K0) + cp * 8]; \
        pb[i][0] = s[0]; pb[i][1] = s[1];                                       \
    }

    LOAD_A(0)
    LOAD_B(0)

    for (int it = 0; it < 8; ++it) {
        __syncthreads();
#pragma unroll
        for (int i = 0; i < 2; ++i) {
            const int P = tid + 256 * i;
            const int row = P >> 3, cp = P & 7;
            uint4 w;
            w.x = cvt2(pa[i][0].x, pa[i][0].y);
            w.y = cvt2(pa[i][0].z, pa[i][0].w);
            w.z = cvt2(pa[i][1].x, pa[i][1].y);
            w.w = cvt2(pa[i][1].z, pa[i][1].w);
            *(uint4*)((char*)Atile + row * 128 + 16 * (cp ^ (row & 7))) = w;
        }
#pragma unroll
        for (int i = 0; i < 4; ++i) {
            const int P = tid + 256 * i;
            const int row = P >> 3, cp = P & 7;
            uint4 w;
            w.x = cvt2(pb[i][0].x, pb[i][0].y);
            w.y = cvt2(pb[i][0].z, pb[i][0].w);
            w.z = cvt2(pb[i][1].x, pb[i][1].y);
            w.w = cvt2(pb[i][1].z, pb[i][1].w);
            *(uint4*)((char*)Btile + row * 128 + 16 * (cp ^ (row & 7))) = w;
        }
        __syncthreads();

        if (it < 7) {
            const int kn = (it + 1) * 64;
            LOAD_A(kn)
            LOAD_B(kn)
        }

        short8 af[2][2], bfr[4][2];
#pragma unroll
        for (int mi = 0; mi < 2; ++mi)
#pragma unroll
            for (int kh = 0; kh < 2; ++kh) {
                const int row = wr * 32 + mi * 16 + lq;
                af[mi][kh] = *(const short8*)((const char*)Atile + row * 128 +
                                              16 * ((kh * 4 + lg) ^ (row & 7)));
            }
#pragma unroll
        for (int ni = 0; ni < 4; ++ni)
#pragma unroll
            for (int kh = 0; kh < 2; ++kh) {
                const int row = wc * 64 + ni * 16 + lq;
                bfr[ni][kh] = *(const short8*)((const char*)Btile + row * 128 +
                                               16 * ((kh * 4 + lg) ^ (row & 7)));
            }
        __builtin_amdgcn_s_setprio(1);
#pragma unroll
        for (int kh = 0; kh < 2; ++kh)
#pragma unroll
            for (int mi = 0; mi < 2; ++mi)
#pragma unroll
                for (int ni = 0; ni < 4; ++ni)
                    acc[mi][ni] = __builtin_amdgcn_mfma_f32_16x16x32_bf16(
                        af[mi][kh], bfr[ni][kh], acc[mi][ni], 0, 0, 0);
        __builtin_amdgcn_s_setprio(0);
    }
#undef LOAD_A
#undef LOAD_B

    if (z < 2) {
        ushort* out = (z == 0) ? qb : kb;
#pragma unroll
        for (int mi = 0; mi < 2; ++mi) {
            const int mb = m0 + wr * 32 + mi * 16 + lg * 4;
#pragma unroll
            for (int ni = 0; ni < 4; ++ni) {
                const int n = n0 + wc * 64 + ni * 16 + lq;
                const int h = n >> 6, d = n & 63;
                const float bb = bias[n];
#pragma unroll
                for (int r = 0; r < 4; ++r) {
                    const int m = mb + r;
                    const int bidx = m >> 9, s = m & 511;
                    out[((size_t)(bidx * NH + h) * SLEN + s) * DK + d] =
                        bf16_1(acc[mi][ni][r] + bb);
                }
            }
        }
    } else {
        // fp16 transposed V [bh][64][s]
#pragma unroll
        for (int mi = 0; mi < 2; ++mi) {
            const int mb = m0 + wr * 32 + mi * 16 + lg * 4;
            const int bidx = mb >> 9, s0 = mb & 511;
#pragma unroll
            for (int ni = 0; ni < 4; ++ni) {
                const int n = n0 + wc * 64 + ni * 16 + lq;
                const int h = n >> 6, d = n & 63;
                const float bb = bias[n];
                uint2 pk;
                pk.x = pk_f16(acc[mi][ni][0] + bb, acc[mi][ni][1] + bb);
                pk.y = pk_f16(acc[mi][ni][2] + bb, acc[mi][ni][3] + bb);
                *(uint2*)&vt[((size_t)(bidx * NH + h) * DK + d) * SLEN + s0] = pk;
            }
        }
    }
}

// ---------------------------------------------------------------------------
// Final projection GEMM: bf16 X (concat) -> fp32 out. Validated r9.
// ---------------------------------------------------------------------------
__global__ __launch_bounds__(256) void gemm_out(
    const ushort* __restrict__ Xb, const float* __restrict__ W,
    const float* __restrict__ bias, float* __restrict__ out)
{
    __shared__ alignas(16) ushort Atile[64 * 64];
    __shared__ alignas(16) ushort Btile[128 * 64];

    const int tid = threadIdx.x;
    const int wave = tid >> 6, lane = tid & 63;
    const int lq = lane & 15, lg = lane >> 4;
    const int wr = wave >> 1, wc = wave & 1;
    const int m0 = blockIdx.x * 64;
    const int n0 = blockIdx.y * 128;

    f32x4 acc[2][4];
#pragma unroll
    for (int i = 0; i < 2; ++i)
#pragma unroll
        for (int j = 0; j < 4; ++j) acc[i][j] = (f32x4){0.f, 0.f, 0.f, 0.f};

    uint4  qa[2];
    float4 pb[4][2];

#define LOAD_A(K0)                                                              \
    _Pragma("unroll")                                                           \
    for (int i = 0; i < 2; ++i) {                                               \
        const int P = tid + 256 * i;                                            \
        const int row = P >> 3, sl = P & 7;                                     \
        qa[i] = *(const uint4*)&Xb[(size_t)(m0 + row) * 512 + (K0) + sl * 8];   \
    }
#define LOAD_B(K0)                                                              \
    _Pragma("unroll")                                                           \
    for (int i = 0; i < 4; ++i) {                                               \
        const int P = tid + 256 * i;                                            \
        const int row = P >> 3, cp = P & 7;                                     \
        const float4* s = (const float4*)&W[(size_t)(n0 + row) * 512 + (K0) + cp * 8]; \
        pb[i][0] = s[0]; pb[i][1] = s[1];                                       \
    }

    LOAD_A(0)
    LOAD_B(0)

    for (int it = 0; it < 8; ++it) {
        __syncthreads();
#pragma unroll
        for (int i = 0; i < 2; ++i) {
            const int P = tid + 256 * i;
            const int row = P >> 3, sl = P & 7;
            *(uint4*)((char*)Atile + row * 128 + 16 * (sl ^ (row & 7))) = qa[i];
        }
#pragma unroll
        for (int i = 0; i < 4; ++i) {
            const int P = tid + 256 * i;
            const int row = P >> 3, cp = P & 7;
            uint4 w;
            w.x = cvt2(pb[i][0].x, pb[i][0].y);
            w.y = cvt2(pb[i][0].z, pb[i][0].w);
            w.z = cvt2(pb[i][1].x, pb[i][1].y);
            w.w = cvt2(pb[i][1].z, pb[i][1].w);
            *(uint4*)((char*)Btile + row * 128 + 16 * (cp ^ (row & 7))) = w;
        }
        __syncthreads();

        if (it < 7) {
            const int kn = (it + 1) * 64;
            LOAD_A(kn)
            LOAD_B(kn)
        }

        short8 af[2][2], bfr[4][2];
#pragma unroll
        for (int mi = 0; mi < 2; ++mi)
#pragma unroll
            for (int kh = 0; kh < 2; ++kh) {
                const int row = wr * 32 + mi * 16 + lq;
                af[mi][kh] = *(const short8*)((const char*)Atile + row * 128 +
                                              16 * ((kh * 4 + lg) ^ (row & 7)));
            }
#pragma unroll
        for (int ni = 0; ni < 4; ++ni)
#pragma unroll
            for (int kh = 0; kh < 2; ++kh) {
                const int row = wc * 64 + ni * 16 + lq;
                bfr[ni][kh] = *(const short8*)((const char*)Btile + row * 128 +
                                               16 * ((kh * 4 + lg) ^ (row & 7)));
            }
        __builtin_amdgcn_s_setprio(1);
#pragma unroll
        for (int kh = 0; kh < 2; ++kh)
#pragma unroll
            for (int mi = 0; mi < 2; ++mi)
#pragma unroll
                for (int ni = 0; ni < 4; ++ni)
                    acc[mi][ni] = __builtin_amdgcn_mfma_f32_16x16x32_bf16(
                        af[mi][kh], bfr[ni][kh], acc[mi][ni], 0, 0, 0);
        __builtin_amdgcn_s_setprio(0);
    }
#undef LOAD_A
#undef LOAD_B

#pragma unroll
    for (int mi = 0; mi < 2; ++mi) {
        const int mb = m0 + wr * 32 + mi * 16 + lg * 4;
#pragma unroll
        for (int ni = 0; ni < 4; ++ni) {
            const int n = n0 + wc * 64 + ni * 16 + lq;
            const float bb = bias[n];
#pragma unroll
            for (int r = 0; r < 4; ++r)
                out[(size_t)(mb + r) * 512 + n] = acc[mi][ni][r] + bb;
        }
    }
}

// ---------------------------------------------------------------------------
// Bias -> fp16, linear chunk layout inside the attn region. Validated r10.
// ---------------------------------------------------------------------------
__global__ __launch_bounds__(512) void bias_kernel(
    const float* __restrict__ dtw, const float* __restrict__ Wd,
    const float* __restrict__ bd, _Float16* __restrict__ bias16)
{
    __shared__ float wdl[NH * DC];
    __shared__ float bdl[NH];
    const int k = threadIdx.x;
    const int q = blockIdx.x;
    const int b = blockIdx.y;
    if (k < NH * DC) wdl[k] = Wd[k];
    if (k < NH) bdl[k] = bd[k];
    __syncthreads();

    float acc[NH];
#pragma unroll
    for (int h = 0; h < NH; ++h) acc[h] = bdl[h];

    const float* p = dtw + ((size_t)b * DC * SLEN + q) * SLEN + k;
#pragma unroll
    for (int c = 0; c < DC; ++c) {
        const float x = p[(size_t)c * SLEN * SLEN];
#pragma unroll
        for (int h = 0; h < NH; ++h) acc[h] += x * wdl[h * DC + c];
    }
    const int q16 = q & ~15, ql = q & 15;
#pragma unroll
    for (int h = 0; h < NH; ++h) {
        const size_t base = bias_chunk_base(b * NH + h, q16);
        bias16[base + (size_t)ql * SLEN + k] = (_Float16)acc[h];
    }
}

// ---------------------------------------------------------------------------
// K-split MFMA attention: block = 32 q-rows, 4 waves = 2 q-slices x 2 k-halves.
// 8192 waves total (2x r10) at 4 waves/SIMD occupancy (VGPR <= 128: ep[16]).
// Wave (qs,kh): QK^T over 16 kt in k-half kh -> ep[16] packed fp16 + partial
// sum; LDS sum-combine (barrier); c2 loop {attn store (own k-half), LDS
// bounce, partial PV}; barrier; kh=0 merges PV partials and writes concat.
// ---------------------------------------------------------------------------
__global__ __launch_bounds__(256, 4) void attn_mfma(
    const ushort* __restrict__ qb, const ushort* __restrict__ kb,
    const ushort* __restrict__ vt, float* __restrict__ attn,
    ushort* __restrict__ concat)
{
    __shared__ alignas(16) ushort Pbuf[4][2][16][32];   // 8 KB bounce (per-wave)
    __shared__ alignas(16) float  Ored[2][16][68];      // 8.5 KB PV partials (padded)
    __shared__ float SumBuf[2][2][16];                  // 256 B

    const int tid = threadIdx.x;
    const int wave = tid >> 6;
    const int lane = tid & 63;
    const int lq = lane & 15;
    const int lg = lane >> 4;
    const int qs = wave >> 1;          // q-slice in block
    const int kh = wave & 1;           // k-half

    // XCD swizzle: 16 consecutive dispatches per XCD share one (b,h)
    const unsigned l = blockIdx.x;                  // 0..2047
    const int g  = (int)((l & 7) + 8 * (l >> 7));   // (b,h) 0..127
    const int qt = (int)((l >> 3) & 15);            // 32-row q-tile
    const int h = g & 7, b = g >> 3;
    const int bh = b * NH + h;
    const int q0 = qt * 32 + qs * 16;

    const ushort* qptr = qb + ((size_t)bh * SLEN + q0) * DK;
    const ushort* kptr = kb + ((size_t)bh * SLEN + kh * 256) * DK;
    const ushort* vptr = vt + (size_t)bh * DK * SLEN;   // fp16 bits
    float* attn_b = attn + ((size_t)bh * SLEN + q0) * SLEN;
    const _Float16* bias_row =
        (const _Float16*)attn + bias_chunk_base(bh, q0) + (size_t)lq * SLEN + kh * 256;

    const short8 qf0 = *(const short8*)&qptr[(size_t)lq * DK + lg * 8];
    const short8 qf1 = *(const short8*)&qptr[(size_t)lq * DK + lg * 8 + 32];

    float sum = 0.f;
    u32x2 ep[16];                       // packed fp16 e (32 VGPR)

#pragma unroll
    for (int ktl = 0; ktl < 16; ++ktl) {
        const short8 a0 = *(const short8*)&kptr[(size_t)(ktl * 16 + lq) * DK + lg * 8];
        const short8 a1 = *(const short8*)&kptr[(size_t)(ktl * 16 + lq) * DK + lg * 8 + 32];
        f32x4 c = {0.f, 0.f, 0.f, 0.f};
        c = __builtin_amdgcn_mfma_f32_16x16x32_bf16(a0, qf0, c, 0, 0, 0);
        c = __builtin_amdgcn_mfma_f32_16x16x32_bf16(a1, qf1, c, 0, 0, 0);
        const h16x4a b4 = *(const h16x4a*)&bias_row[ktl * 16 + 4 * lg];
        const float e0 = __expf(c[0] * 0.125f + (float)b4[0]);
        const float e1 = __expf(c[1] * 0.125f + (float)b4[1]);
        const float e2 = __expf(c[2] * 0.125f + (float)b4[2]);
        const float e3 = __expf(c[3] * 0.125f + (float)b4[3]);
        sum += (e0 + e1) + (e2 + e3);
        u32x2 pk;
        pk[0] = pk_f16(e0, e1);
        pk[1] = pk_f16(e2, e3);
        ep[ktl] = pk;
    }
    sum += __shfl_xor(sum, 16);
    sum += __shfl_xor(sum, 32);
    if (lg == 0) SumBuf[qs][kh][lq] = sum;       // all bias reads done by here
    __syncthreads();
    const float inv = 1.0f / (SumBuf[qs][0][lq] + SumBuf[qs][1][lq]);

    f32x4 oacc[4] = {{0.f,0.f,0.f,0.f},{0.f,0.f,0.f,0.f},{0.f,0.f,0.f,0.f},{0.f,0.f,0.f,0.f}};

#pragma unroll
    for (int c2 = 0; c2 < 8; ++c2) {
        char* pbb = (char*)&Pbuf[wave][c2 & 1][0][0];
#pragma unroll
        for (int t = 0; t < 2; ++t) {
            const int ktl = 2 * c2 + t;
            // fp32 attn store (own k-half) = unpack(fp16 e) * inv
            const h16x4 hv = __builtin_bit_cast(h16x4, ep[ktl]);
            f32x4 a;
            a[0] = (float)hv[0] * inv;
            a[1] = (float)hv[1] * inv;
            a[2] = (float)hv[2] * inv;
            a[3] = (float)hv[3] * inv;
            *(f32x4*)&attn_b[(size_t)lq * SLEN + kh * 256 + ktl * 16 + lg * 4] = a;
            // LDS bounce (validated layout)
            const int slot = (t * 2 + (lg >> 1)) ^ (lq & 3);
            *(u32x2*)(pbb + lq * 64 + slot * 16 + (lg & 1) * 8) = ep[ktl];
        }
        asm volatile("s_waitcnt lgkmcnt(0)" ::: "memory");

        const h16x8 pa = *(const h16x8*)(pbb + lq * 64 + (lg ^ (lq & 3)) * 16);
        __builtin_amdgcn_s_setprio(1);
#pragma unroll
        for (int dt = 0; dt < 4; ++dt) {
            const h16x8 vb8 = *(const h16x8*)
                &vptr[(size_t)(dt * 16 + lq) * SLEN + (kh * 8 + c2) * 32 + lg * 8];
            oacc[dt] = __builtin_amdgcn_mfma_f32_16x16x32_f16(pa, vb8, oacc[dt], 0, 0, 0);
        }
        __builtin_amdgcn_s_setprio(0);
    }

    // combine PV partials across the k-half pair
    if (kh == 1) {
#pragma unroll
        for (int dt = 0; dt < 4; ++dt)
#pragma unroll
            for (int r = 0; r < 4; ++r)
                Ored[qs][lg * 4 + r][dt * 16 + lq] = oacc[dt][r];
    }
    __syncthreads();
    if (kh == 0) {
        ushort* cbase = concat + ((size_t)(b * SLEN + q0)) * DM + h * 64;
#pragma unroll
        for (int r = 0; r < 4; ++r) {
            const float iv = __shfl(inv, lg * 4 + r);
#pragma unroll
            for (int dt = 0; dt < 4; ++dt) {
                const float val = (oacc[dt][r] + Ored[qs][lg * 4 + r][dt * 16 + lq]) * iv;
                cbase[(size_t)(lg * 4 + r) * DM + dt * 16 + lq] = bf16_1(val);
            }
        }
    }
}

// ---------------------------------------------------------------------------
extern "C" void kernel_launch(void* const* d_in, const int* in_sizes, int n_in,
                              void* d_out, int out_size, void* d_ws, size_t ws_size,
                              hipStream_t stream)
{
    const float* Q   = (const float*)d_in[0];
    const float* K   = (const float*)d_in[1];
    const float* V   = (const float*)d_in[2];
    const float* dtw = (const float*)d_in[4];
    const float* Wq  = (const float*)d_in[5];
    const float* bq  = (const float*)d_in[6];
    const float* Wk  = (const float*)d_in[7];
    const float* bk  = (const float*)d_in[8];
    const float* Wv  = (const float*)d_in[9];
    const float* bv  = (const float*)d_in[10];
    const float* Wd  = (const float*)d_in[11];
    const float* bd  = (const float*)d_in[12];
    const float* Wo  = (const float*)d_in[13];
    const float* bo  = (const float*)d_in[14];

    float* out  = (float*)d_out;                       // [16,512,512] fp32
    float* attn = out + (size_t)BS * SLEN * DM;        // [16,8,512,512] fp32
    _Float16* bias16 = (_Float16*)attn;                // fp16 bias chunks inside attn region

    const size_t PHS = (size_t)BS * NH * SLEN * DK;    // 4,194,304 elements
    ushort* qb = (ushort*)d_ws;
    ushort* kb = qb + PHS;
    ushort* vt = kb + PHS;                             // fp16 V
    ushort* cb = vt + PHS;                             // concat bf16 [16,512,512]

    gemm_qkv<<<dim3(128, 4, 3), 256, 0, stream>>>(Q, K, V, Wq, Wk, Wv,
                                                  bq, bk, bv, qb, kb, vt);

    bias_kernel<<<dim3(SLEN, BS), 512, 0, stream>>>(dtw, Wd, bd, bias16);

    attn_mfma<<<dim3(2048), 256, 0, stream>>>(qb, kb, vt, attn, cb);

    gemm_out<<<dim3(128, 4), 256, 0, stream>>>(cb, Wo, bo, out);
}